// Round 1
// baseline (902.016 us; speedup 1.0000x reference)
//
#include <hip/hip_runtime.h>
#include <math.h>

#define HGRID 128
#define WGRID 128
#define NPTS 16
#define TSTEPS 500

// 4-round DPP butterfly: every lane ends with the sum of its 16-lane row.
// ctrl: 0xB1 = quad_perm[1,0,3,2] (xor1), 0x4E = quad_perm[2,3,0,1] (xor2),
//       0x141 = row_half_mirror (pairs 8-groups), 0x140 = row_mirror (pairs 16-halves)
__device__ __forceinline__ float dpp_sum16(float v) {
    int x;
    x = __builtin_amdgcn_update_dpp(0, __float_as_int(v), 0xB1, 0xF, 0xF, true);
    v += __int_as_float(x);
    x = __builtin_amdgcn_update_dpp(0, __float_as_int(v), 0x4E, 0xF, 0xF, true);
    v += __int_as_float(x);
    x = __builtin_amdgcn_update_dpp(0, __float_as_int(v), 0x141, 0xF, 0xF, true);
    v += __int_as_float(x);
    x = __builtin_amdgcn_update_dpp(0, __float_as_int(v), 0x140, 0xF, 0xF, true);
    v += __int_as_float(x);
    return v;
}

// Bilinear interp on the LDS-staged grid, faithful to reference _interp.
__device__ __forceinline__ float interp1(const float* __restrict__ sg, float xq, float yq) {
    float xi = (xq + 6.4f) / 0.1f;
    xi = fminf(fmaxf(xi, 0.0f), 126.0f);
    float yi = (yq + 6.4f) / 0.1f;
    yi = fminf(fmaxf(yi, 0.0f), 126.0f);
    float fx = floorf(xi);
    float fy = floorf(yi);
    int x0 = (int)fx;
    int y0 = (int)fy;
    float wx = xi - fx;
    float wy = yi - fy;
    const float* r0 = sg + (x0 * WGRID + y0);
    float z00 = r0[0];
    float z01 = r0[1];
    float z10 = r0[WGRID];
    float z11 = r0[WGRID + 1];
    float ox = 1.0f - wx, oy = 1.0f - wy;
    return z00 * ox * oy + z10 * wx * oy + z01 * ox * wy + z11 * wx * wy;
}

extern "C" __global__ __launch_bounds__(64, 1) void dphys_sim(
    const float* __restrict__ z_grid,
    const float* __restrict__ controls,
    const float* __restrict__ robot_points,
    const float* __restrict__ I_inv,
    float* __restrict__ out)
{
    __shared__ float sg[HGRID * WGRID];   // 64 KB: one batch's height grid

    const int b = blockIdx.x;
    const int lane = threadIdx.x;

    // ---- stage grid into LDS (float4, coalesced) ----
    {
        const float4* src = (const float4*)(z_grid + (size_t)b * (HGRID * WGRID));
        float4* dst = (float4*)sg;
        #pragma unroll 4
        for (int i = lane; i < (HGRID * WGRID) / 4; i += 64) dst[i] = src[i];
    }

    // I_inv: uniform -> lives in SGPRs
    const float i00 = I_inv[0], i01 = I_inv[1], i02 = I_inv[2];
    const float i10 = I_inv[3], i11 = I_inv[4], i12 = I_inv[5];
    const float i20 = I_inv[6], i21 = I_inv[7], i22 = I_inv[8];

    // point for this lane (4x redundant across quarter-waves)
    const int p = lane & 15;
    const float rpx = robot_points[3 * p + 0];
    const float rpy = robot_points[3 * p + 1];
    const float rpz = robot_points[3 * p + 2];

    // cog.y via row reduction (exact: ys are +-0.25) -> left/right mask
    const float cog_y = dpp_sum16(rpy) * (1.0f / 16.0f);
    const bool is_left = rpy > cog_y;

    __syncthreads();

    const float K_STIFF = 5000.0f;
    const float K_DAMP  = 894.4271909999159f;   // sqrt(4*40*5000)
    const float K_FRIC  = 0.5f;
    const float DTC     = 0.01f;
    const float EPSF    = 1e-6f;
    // rk4 with constant derivative: x + d * CRK, CRK = dt*(1+dt/2+dt^2/6+dt^3/24)
    const float CRK     = 0.010050166708416667f;

    // state (scalar state redundant in every lane)
    float X = 0.f, Y = 0.f, Z = 1.f;
    float VX = 0.f, VY = 0.f, VZ = 0.f;
    float R00 = 1.f, R01 = 0.f, R02 = 0.f;
    float R10 = 0.f, R11 = 1.f, R12 = 0.f;
    float R20 = 0.f, R21 = 0.f, R22 = 1.f;
    float OX = 0.f, OY = 0.f, OZ = 0.f;
    float px = rpx, py = rpy, pz = rpz + 1.0f;   // x_points
    float pvx = 0.f, pvy = 0.f, pvz = 0.f;       // xd_points

    float* outb = out + (size_t)b * TSTEPS * 162;
    const float* cg = controls + (size_t)b * (TSTEPS * 2);

    // prefetch controls for t=0
    float u_l = cg[0], u_r = cg[1];

    #pragma unroll 1
    for (int t = 0; t < TSTEPS; ++t) {
        // prefetch next step's controls (hidden under this step's compute)
        const int tn = (t + 1 < TSTEPS) ? (t + 1) : t;
        const float u_l_nxt = cg[2 * tn + 0];
        const float u_r_nxt = cg[2 * tn + 1];

        // ---- terrain queries: 5 bilinear interps per point ----
        const float z_pt = interp1(sg, px, py);
        const float zpx  = interp1(sg, px + 0.1f, py);
        const float zmx  = interp1(sg, px - 0.1f, py);
        const float zpy  = interp1(sg, px, py + 0.1f);
        const float zmy  = interp1(sg, px, py - 0.1f);

        const float dh = pz - z_pt;
        const bool on = (px >= -6.4f) && (px <= 6.4f) && (py >= -6.4f) && (py <= 6.4f);
        const float contact = ((dh <= 0.0f) && on) ? 1.0f : 0.0f;

        // surface normal
        const float dzdx = (zpx - zmx) / 0.2f;
        const float dzdy = (zpy - zmy) / 0.2f;
        float nx = -dzdx, ny = -dzdy, nz = 1.0f;
        const float nn = sqrtf(nx * nx + ny * ny + nz * nz) + EPSF;
        nx /= nn; ny /= nn; nz /= nn;

        // spring + damping along normal
        const float xd_n = pvx * nx + pvy * ny + pvz * nz;
        const float s_mag = -(K_STIFF * dh + K_DAMP * xd_n);
        const float fsx = s_mag * nx * contact;
        const float fsy = s_mag * ny * contact;
        const float fsz = s_mag * nz * contact;

        const float Nmag = sqrtf(fsx * fsx + fsy * fsy + fsz * fsz);

        // thrust = normalized first column of R
        float tx = R00, ty = R10, tz = R20;
        const float tnn = sqrtf(tx * tx + ty * ty + tz * tz) + EPSF;
        tx /= tnn; ty /= tnn; tz /= tnn;

        // friction (each point uses only its side's control)
        const float u_sel = is_left ? u_l : u_r;
        const float kn = K_FRIC * Nmag;
        const float ffx = kn * tanhf(u_sel * tx - pvx);
        const float ffy = kn * tanhf(u_sel * ty - pvy);
        const float ffz = kn * tanhf(u_sel * tz - pvz);

        // torque contribution
        const float rx = px - X, ry = py - Y, rz = pz - Z;
        const float Fx = fsx + ffx, Fy = fsy + ffy, Fz = fsz + ffz;
        const float tqx = ry * Fz - rz * Fy;
        const float tqy = rz * Fx - rx * Fz;
        const float tqz = rx * Fy - ry * Fx;

        // ---- 16-point reductions (DPP butterflies; all lanes get the sum) ----
        const float Tqx = dpp_sum16(tqx);
        const float Tqy = dpp_sum16(tqy);
        const float Tqz = dpp_sum16(tqz);
        const float Ssx = dpp_sum16(fsx);
        const float Ssy = dpp_sum16(fsy);
        const float Ssz = dpp_sum16(fsz);
        const float Sfx = dpp_sum16(ffx);
        const float Sfy = dpp_sum16(ffy);
        const float Sfz = dpp_sum16(ffz);

        // omega_dot = I_inv @ torque
        const float odx = i00 * Tqx + i01 * Tqy + i02 * Tqz;
        const float ody = i10 * Tqx + i11 * Tqy + i12 * Tqz;
        const float odz = i20 * Tqx + i21 * Tqy + i22 * Tqz;

        // F_cog and accel ( /16 is exact; keep reference's add order; divide by MASS )
        const float Fcx = Ssx * 0.0625f + Sfx * 0.0625f;
        const float Fcy = Ssy * 0.0625f + Sfy * 0.0625f;
        const float Fcz = -392.4f + Ssz * 0.0625f + Sfz * 0.0625f;
        const float axd = Fcx / 40.0f;
        const float ayd = Fcy / 40.0f;
        const float azd = Fcz / 40.0f;

        // xd_points_new from OLD xd, OLD omega
        const float cpx = OY * rz - OZ * ry;
        const float cpy = OZ * rx - OX * rz;
        const float cpz = OX * ry - OY * rx;
        const float pvnx = VX + cpx, pvny = VY + cpy, pvnz = VZ + cpz;

        // integrate (rk4 closed form)
        const float VXn = fmaf(axd, CRK, VX);
        const float VYn = fmaf(ayd, CRK, VY);
        const float VZn = fmaf(azd, CRK, VZ);
        const float Xn = fmaf(VXn, CRK, X);
        const float Yn = fmaf(VYn, CRK, Y);
        const float Zn = fmaf(VZn, CRK, Z);
        const float pxn = fmaf(pvnx, CRK, px);
        const float pyn = fmaf(pvny, CRK, py);
        const float pzn = fmaf(pvnz, CRK, pz);
        const float OXn = fmaf(odx, CRK, OX);
        const float OYn = fmaf(ody, CRK, OY);
        const float OZn = fmaf(odz, CRK, OZ);

        // rotation integration with omega_new (Rodrigues, skew^2 in closed form)
        const float th = sqrtf(OXn * OXn + OYn * OYn + OZn * OZn);
        const float inv = 1.0f / (th + EPSF);
        const float axn = OXn * inv, ayn = OYn * inv, azn = OZn * inv;
        const float sth = sinf(th * DTC);
        const float cth = 1.0f - cosf(th * DTC);
        const float M00 = 1.0f - (ayn * ayn + azn * azn) * cth;
        const float M01 = -azn * sth + axn * ayn * cth;
        const float M02 =  ayn * sth + axn * azn * cth;
        const float M10 =  azn * sth + axn * ayn * cth;
        const float M11 = 1.0f - (axn * axn + azn * azn) * cth;
        const float M12 = -axn * sth + ayn * azn * cth;
        const float M20 = -ayn * sth + axn * azn * cth;
        const float M21 =  axn * sth + ayn * azn * cth;
        const float M22 = 1.0f - (axn * axn + ayn * ayn) * cth;

        const float nR00 = R00 * M00 + R01 * M10 + R02 * M20;
        const float nR01 = R00 * M01 + R01 * M11 + R02 * M21;
        const float nR02 = R00 * M02 + R01 * M12 + R02 * M22;
        const float nR10 = R10 * M00 + R11 * M10 + R12 * M20;
        const float nR11 = R10 * M01 + R11 * M11 + R12 * M21;
        const float nR12 = R10 * M02 + R11 * M12 + R12 * M22;
        const float nR20 = R20 * M00 + R21 * M10 + R22 * M20;
        const float nR21 = R20 * M01 + R21 * M11 + R22 * M21;
        const float nR22 = R20 * M02 + R21 * M12 + R22 * M22;

        // ---- output: [x(3) xd(3) omega(3) R(9) xpts(48) Fs(48) Ff(48)] ----
        float* ob = outb + (size_t)t * 162;
        if (lane == 0) {
            ob[0] = Xn;  ob[1] = Yn;  ob[2] = Zn;
            ob[3] = VXn; ob[4] = VYn; ob[5] = VZn;
            ob[6] = OXn; ob[7] = OYn; ob[8] = OZn;
            ob[9]  = nR00; ob[10] = nR01; ob[11] = nR02;
            ob[12] = nR10; ob[13] = nR11; ob[14] = nR12;
            ob[15] = nR20; ob[16] = nR21; ob[17] = nR22;
        }
        if (lane < 16) {
            float* o1 = ob + 18 + 3 * lane;
            o1[0] = pxn; o1[1] = pyn; o1[2] = pzn;
            float* o2 = ob + 66 + 3 * lane;
            o2[0] = fsx; o2[1] = fsy; o2[2] = fsz;
            float* o3 = ob + 114 + 3 * lane;
            o3[0] = ffx; o3[1] = ffy; o3[2] = ffz;
        }

        // commit state
        X = Xn; Y = Yn; Z = Zn;
        VX = VXn; VY = VYn; VZ = VZn;
        px = pxn; py = pyn; pz = pzn;
        pvx = pvnx; pvy = pvny; pvz = pvnz;
        OX = OXn; OY = OYn; OZ = OZn;
        R00 = nR00; R01 = nR01; R02 = nR02;
        R10 = nR10; R11 = nR11; R12 = nR12;
        R20 = nR20; R21 = nR21; R22 = nR22;

        u_l = u_l_nxt; u_r = u_r_nxt;
    }
}

extern "C" void kernel_launch(void* const* d_in, const int* in_sizes, int n_in,
                              void* d_out, int out_size, void* d_ws, size_t ws_size,
                              hipStream_t stream) {
    const float* z_grid       = (const float*)d_in[0];
    const float* controls     = (const float*)d_in[1];
    const float* robot_points = (const float*)d_in[2];
    const float* I_inv        = (const float*)d_in[3];
    // d_in[4]/d_in[5] (mask_left/mask_right) are derivable from robot_points; unused.
    float* out = (float*)d_out;

    const int B = in_sizes[0] / (HGRID * WGRID);   // 256
    dphys_sim<<<dim3(B), dim3(64), 0, stream>>>(z_grid, controls, robot_points, I_inv, out);
}